// Round 4
// baseline (106.618 us; speedup 1.0000x reference)
//
#include <hip/hip_runtime.h>
#include <hip/hip_bf16.h>
#include <math.h>

#define DD 1024          // D (in == out features)
#define BT 8192          // B*N tokens
#define TWO_PI 6.28318530717958647692f

typedef float f32x4 __attribute__((ext_vector_type(4)));
typedef short bf16x8 __attribute__((ext_vector_type(8)));
typedef unsigned short u16x8 __attribute__((ext_vector_type(8)));
typedef unsigned short u16x4 __attribute__((ext_vector_type(4)));
typedef const __attribute__((address_space(1))) void g_void;
typedef __attribute__((address_space(3))) void l_void;

__device__ __forceinline__ unsigned short f2bf(float f) {
  unsigned int u = __float_as_uint(f);
  unsigned int r = (u + 0x7FFFu + ((u >> 16) & 1u)) >> 16;   // RNE
  return (unsigned short)r;
}

// ---------------------------------------------------------------------------
// Transpose W (Wr,Wi fp32 (k,o)) -> Wt float2 (o,k), coalesced both sides.
// ---------------------------------------------------------------------------
__global__ __launch_bounds__(256) void transpose_W_kernel(
    const float* __restrict__ Wr, const float* __restrict__ Wi,
    float2* __restrict__ Wt) {
  __shared__ float tr[64][65];
  __shared__ float ti[64][65];
  const int k0 = blockIdx.y * 64, o0 = blockIdx.x * 64;
  for (int q = threadIdx.x; q < 64 * 64; q += 256) {
    int r = q >> 6, c = q & 63;                 // r: k, c: o
    tr[r][c] = Wr[(size_t)(k0 + r) * DD + o0 + c];
    ti[r][c] = Wi[(size_t)(k0 + r) * DD + o0 + c];
  }
  __syncthreads();
  for (int q = threadIdx.x; q < 64 * 64; q += 256) {
    int r = q >> 6, c = q & 63;                 // r: o, c: k
    Wt[(size_t)(o0 + r) * DD + k0 + c] = make_float2(tr[c][r], ti[c][r]);
  }
}

// ---------------------------------------------------------------------------
// T[o][d] = sum_k W[k][o] e^{-2pi i k d/D}. One block per o; compact nonzeros
// of row Wt[o][:] (coalesced) into LDS (parallel prefix), then twiddle table.
// ---------------------------------------------------------------------------
__global__ __launch_bounds__(256) void build_T_kernel(
    const float2* __restrict__ Wt, float2* __restrict__ T) {
  __shared__ float2 tw[DD];
  __shared__ int    kidx[64];
  __shared__ float2 wval[64];
  __shared__ int    sc[256];
  const int o = blockIdx.x, tid = threadIdx.x;

  for (int j = tid; j < DD; j += 256) {
    float s, c;
    sincosf((TWO_PI / DD) * (float)j, &s, &c);
    tw[j] = make_float2(c, s);
  }
  int cnt = 0;
  float2 wl[4];
  int    kl[4];
#pragma unroll
  for (int q = 0; q < 4; q++) {
    int k = tid + q * 256;
    float2 w = Wt[(size_t)o * DD + k];
    if (w.x != 0.f || w.y != 0.f) { wl[cnt] = w; kl[cnt] = k; cnt++; }
  }
  sc[tid] = cnt;
  __syncthreads();
  // Hillis-Steele inclusive scan over 256
#pragma unroll
  for (int dstep = 1; dstep < 256; dstep <<= 1) {
    int v = (tid >= dstep) ? sc[tid - dstep] : 0;
    __syncthreads();
    sc[tid] += v;
    __syncthreads();
  }
  int p = sc[tid] - cnt;
  for (int q = 0; q < cnt; q++) { kidx[p + q] = kl[q]; wval[p + q] = wl[q]; }
  __syncthreads();
  const int nnz = sc[255];
  for (int d = tid; d < DD; d += 256) {
    float re = 0.f, im = 0.f;
    for (int j = 0; j < nnz; j++) {
      int    k  = kidx[j];
      float2 w  = wval[j];
      float2 cs = tw[(k * d) & (DD - 1)];
      re += w.x * cs.x + w.y * cs.y;          // W * e^{-i th}
      im += w.y * cs.x - w.x * cs.y;
    }
    T[(size_t)o * DD + d] = make_float2(re, im);
  }
}

// ---------------------------------------------------------------------------
// TT[d][o] = bf16(Re T[o][d]); TT[d][1024+o] = bf16(Im T[o][d])  (transpose)
// ---------------------------------------------------------------------------
__global__ __launch_bounds__(256) void transpose_T_kernel(
    const float2* __restrict__ T, unsigned short* __restrict__ TT) {
  __shared__ float2 tile[64][65];
  const int o0 = blockIdx.x * 64, d0 = blockIdx.y * 64;
  for (int q = threadIdx.x; q < 64 * 64; q += 256) {
    int r = q >> 6, c = q & 63;                 // r: o, c: d
    tile[r][c] = T[(size_t)(o0 + r) * DD + d0 + c];
  }
  __syncthreads();
  for (int q = threadIdx.x; q < 64 * 64; q += 256) {
    int r = q >> 6, c = q & 63;                 // r: d, c: o
    float2 v = tile[c][r];
    TT[(size_t)(d0 + r) * 2048 + o0 + c]        = f2bf(v.x);
    TT[(size_t)(d0 + r) * 2048 + 1024 + o0 + c] = f2bf(v.y);
  }
}

// ---------------------------------------------------------------------------
// CS[m][o] = bf16(cos(2pi m o/D)); CS[m][1024+o] = bf16(-sin(2pi m o/D))
// ---------------------------------------------------------------------------
__global__ __launch_bounds__(256) void gen_CS_kernel(unsigned short* __restrict__ CS) {
  int idx = blockIdx.x * 256 + threadIdx.x;     // 1M = 1024x1024
  int m = idx >> 10, o = idx & 1023;
  float s, c;
  sincosf((TWO_PI / DD) * (float)((m * o) & (DD - 1)), &s, &c);
  CS[(size_t)m * 2048 + o]        = f2bf(c);
  CS[(size_t)m * 2048 + 1024 + o] = f2bf(-s);
}

// ---------------------------------------------------------------------------
// x fp32 -> bf16 (8 elems/thread)
// ---------------------------------------------------------------------------
__global__ __launch_bounds__(256) void convert_x_kernel(
    const float* __restrict__ X, unsigned short* __restrict__ Xb) {
  size_t i = (size_t)blockIdx.x * 256 + threadIdx.x;   // chunk of 8
  const float4* p = (const float4*)(X + i * 8);
  float4 a = p[0], b = p[1];
  u16x8 v;
  v[0] = f2bf(a.x); v[1] = f2bf(a.y); v[2] = f2bf(a.z); v[3] = f2bf(a.w);
  v[4] = f2bf(b.x); v[5] = f2bf(b.y); v[6] = f2bf(b.z); v[7] = f2bf(b.w);
  *(u16x8*)(Xb + i * 8) = v;
}

// ---------------------------------------------------------------------------
// NT bf16 MFMA GEMM: Out[r][c] = sum_k A[r][k]*B[c][k]
// 128x128 tile, 4 waves (2x2), 4x4 frags of 16x16x32, BK=64 double-stage
// (two 32-wide LDS halves per barrier pair), global_load_lds width 16.
// 1-D grid + chunked XCD swizzle: 8 consecutive row-panels per XCD so the
// per-XCD working set (X chunk + all of B) fits the 4 MB XCD L2.
// GX = col-tiles. MODE 0: fp32 out, *scale+bias. MODE 2: fp32 partials,
// z = K-chunk index folded into the grid (kLen per chunk).
// ---------------------------------------------------------------------------
template <int LDK, int MODE, int GX>
__global__ __launch_bounds__(256) void mfma_nt_kernel(
    const unsigned short* __restrict__ A,   // (rows x LDK) bf16
    const unsigned short* __restrict__ B,   // (cols x LDK) bf16
    const float* __restrict__ bias,
    float* __restrict__ Out, float scale, int ldo, int kLen) {
  __shared__ __align__(16) unsigned short Asm[2][128 * 32];
  __shared__ __align__(16) unsigned short Bsm[2][128 * 32];
  const int tid  = threadIdx.x;
  const int wave = tid >> 6, lane = tid & 63;
  const int wr = wave >> 1, wc = wave & 1;

  // bijective chunked XCD swizzle (gridDim.x % 8 == 0)
  const int L     = blockIdx.x;
  const int chunk = gridDim.x >> 3;
  const int W     = (L & 7) * chunk + (L >> 3);
  const int tx    = W % GX;
  const int tyz   = W / GX;
  const int ty    = (MODE == 2) ? (tyz & 7) : tyz;
  const int tz    = (MODE == 2) ? (tyz >> 3) : 0;

  const int row0 = ty * 128;
  const int col0 = tx * 128;
  const int kBeg = tz * kLen;

  f32x4 acc[4][4] = {};

  for (int k0 = kBeg; k0 < kBeg + kLen; k0 += 64) {
    __syncthreads();
#pragma unroll
    for (int h = 0; h < 2; h++) {
#pragma unroll
      for (int is = 0; is < 2; is++) {
        int e = is * 256 + tid;
        int r = e >> 2, c = (e & 3) * 8;
        const unsigned short* ga = A + (size_t)(row0 + r) * LDK + k0 + h * 32 + c;
        const unsigned short* gb = B + (size_t)(col0 + r) * LDK + k0 + h * 32 + c;
        __builtin_amdgcn_global_load_lds((g_void*)ga, (l_void*)(Asm[h] + is * 2048 + wave * 512), 16, 0, 0);
        __builtin_amdgcn_global_load_lds((g_void*)gb, (l_void*)(Bsm[h] + is * 2048 + wave * 512), 16, 0, 0);
      }
    }
    __syncthreads();

#pragma unroll
    for (int h = 0; h < 2; h++) {
      bf16x8 af[4], bfr[4];
#pragma unroll
      for (int i = 0; i < 4; i++) {
        int ra = wr * 64 + i * 16 + (lane & 15);
        af[i]  = *(const bf16x8*)&Asm[h][ra * 32 + (lane >> 4) * 8];
        int rb = wc * 64 + i * 16 + (lane & 15);
        bfr[i] = *(const bf16x8*)&Bsm[h][rb * 32 + (lane >> 4) * 8];
      }
#pragma unroll
      for (int i = 0; i < 4; i++)
#pragma unroll
        for (int j = 0; j < 4; j++)
          acc[i][j] = __builtin_amdgcn_mfma_f32_16x16x32_bf16(af[i], bfr[j], acc[i][j], 0, 0, 0);
    }
  }

  const int crow0 = row0 + wr * 64;
  const int ccol0 = col0 + wc * 64;
  if (MODE == 2) {
    float* O = Out + (size_t)tz * DD * DD;
#pragma unroll
    for (int i = 0; i < 4; i++)
#pragma unroll
      for (int j = 0; j < 4; j++) {
        int cc = ccol0 + j * 16 + (lane & 15);
#pragma unroll
        for (int v = 0; v < 4; v++) {
          int rr = crow0 + i * 16 + (lane >> 4) * 4 + v;
          O[(size_t)rr * ldo + cc] = acc[i][j][v];
        }
      }
  } else {
    float bv[4];
#pragma unroll
    for (int j = 0; j < 4; j++)
      bv[j] = bias[ccol0 + j * 16 + (lane & 15)];
#pragma unroll
    for (int i = 0; i < 4; i++)
#pragma unroll
      for (int j = 0; j < 4; j++) {
        int cc = ccol0 + j * 16 + (lane & 15);
#pragma unroll
        for (int v = 0; v < 4; v++) {
          int rr = crow0 + i * 16 + (lane >> 4) * 4 + v;
          Out[(size_t)rr * ldo + cc] = acc[i][j][v] * scale + bv[j];
        }
      }
  }
}

// ---------------------------------------------------------------------------
// Mb[i] = bf16( (P0[i]+P1[i]+P2[i]+P3[i]) / D ),  i over 1M elements, x4 vec.
// ---------------------------------------------------------------------------
__global__ __launch_bounds__(256) void reduce_M_kernel(
    const float* __restrict__ P, unsigned short* __restrict__ Mb) {
  const size_t NE = (size_t)DD * DD;
  size_t i = ((size_t)blockIdx.x * 256 + threadIdx.x) * 4;
  float4 s = *(const float4*)(P + i);
#pragma unroll
  for (int z = 1; z < 4; z++) {
    float4 p = *(const float4*)(P + z * NE + i);
    s.x += p.x; s.y += p.y; s.z += p.z; s.w += p.w;
  }
  const float inv = 1.0f / (float)DD;
  u16x4 v;
  v[0] = f2bf(s.x * inv); v[1] = f2bf(s.y * inv);
  v[2] = f2bf(s.z * inv); v[3] = f2bf(s.w * inv);
  *(u16x4*)(Mb + i) = v;
}

// ---------------------------------------------------------------------------
extern "C" void kernel_launch(void* const* d_in, const int* in_sizes, int n_in,
                              void* d_out, int out_size, void* d_ws, size_t ws_size,
                              hipStream_t stream) {
  const float* x    = (const float*)d_in[0];
  const float* wrp  = (const float*)d_in[1];
  const float* wip  = (const float*)d_in[2];
  const float* bias = (const float*)d_in[3];
  float*       y    = (float*)d_out;

  char* ws = (char*)d_ws;
  const size_t MB = 1024 * 1024;
  // Region 0..16MB is time-shared: Wt (dead after build_T), T at 8..16MB
  // (dead after transpose_T), then P partials, then Xb.
  float2*         Wt = (float2*)(ws + 0);                // 8 MB
  float2*         T  = (float2*)(ws + 8  * MB);          // 8 MB
  unsigned short* TT = (unsigned short*)(ws + 16 * MB);  // 4 MB  [d][2048]
  unsigned short* CS = (unsigned short*)(ws + 20 * MB);  // 4 MB  [m][2048]
  unsigned short* Mb = (unsigned short*)(ws + 24 * MB);  // 2 MB  [m][d]
  float*          P  = (float*)(ws + 0);                 // 16 MB partials
  unsigned short* Xb = (unsigned short*)(ws + 0);        // 16 MB (after reduce)

  transpose_W_kernel<<<dim3(16, 16), 256, 0, stream>>>(wrp, wip, Wt);
  build_T_kernel<<<DD, 256, 0, stream>>>(Wt, T);
  transpose_T_kernel<<<dim3(16, 16), 256, 0, stream>>>(T, TT);
  gen_CS_kernel<<<4096, 256, 0, stream>>>(CS);
  // P[z] = CS(1024x2048) . TT^T over K-chunk z of 512   (split-K x4)
  mfma_nt_kernel<2048, 2, 8><<<256, 256, 0, stream>>>(
      CS, TT, nullptr, P, 1.0f, DD, 512);
  reduce_M_kernel<<<DD * DD / (256 * 4), 256, 0, stream>>>(P, Mb);
  convert_x_kernel<<<4096, 256, 0, stream>>>(x, Xb);
  // Y = Xb(8192x1024) . Mb(1024x1024)^T + bias -> fp32
  mfma_nt_kernel<1024, 0, 8><<<512, 256, 0, stream>>>(
      Xb, Mb, bias, y, 1.0f, DD, 1024);
}